// Round 1
// baseline (1791.391 us; speedup 1.0000x reference)
//
#include <hip/hip_runtime.h>

// ---------------------------------------------------------------------------
// Bidirectional 2-layer GRU (B=256, L=200, IN=512, H=256) + FC heads.
// Pipeline: cast/prep -> gemm(xi l0) -> gru(l0) -> gemm(xi l1) -> gru(out)
//           -> heads1 (fc1/fc2) -> heads2 (softmaxes, y3)
// fp16 MFMA (16x16x32), fp32 accumulate, fp32 elementwise recursion.
// ---------------------------------------------------------------------------

typedef _Float16 half8 __attribute__((ext_vector_type(8)));
typedef _Float16 half4v __attribute__((ext_vector_type(4)));
typedef float fx4 __attribute__((ext_vector_type(4)));

#define BATCH 256
#define SEQ   200
#define HID   256
#define MROWS (BATCH*SEQ)   // 51200
#define NG    1536          // 3H * 2 directions
#define KDIM  512           // layer0 input = 512, layer1 input = 2H = 512

// ---------------------------- prep kernels ---------------------------------

__global__ __launch_bounds__(256) void k_cast_x(const float4* __restrict__ x,
                                                half4v* __restrict__ xh, int n4) {
  int i = blockIdx.x * 256 + threadIdx.x;
  if (i < n4) {
    float4 v = x[i];
    half4v o;
    o[0] = (_Float16)v.x; o[1] = (_Float16)v.y; o[2] = (_Float16)v.z; o[3] = (_Float16)v.w;
    xh[i] = o;
  }
}

// Build concatenated input-projection weights [1536][512] fp16 + bias [1536] fp32
__global__ __launch_bounds__(256) void k_prep_wih(const float* __restrict__ wf,
                                                  const float* __restrict__ wr,
                                                  const float* __restrict__ bf_,
                                                  const float* __restrict__ br_,
                                                  _Float16* __restrict__ wcat,
                                                  float* __restrict__ bcat) {
  int idx = blockIdx.x * 256 + threadIdx.x;     // < 1536*512 = 786432
  int n = idx >> 9;
  float v = (n < 768) ? wf[idx] : wr[idx - 768 * 512];
  wcat[idx] = (_Float16)v;
  if (idx < 1536) bcat[idx] = (idx < 768) ? bf_[idx] : br_[idx - 768];
}

// Pack w_hh into MFMA B-fragment order: [dir][w(16)][gate(3)][kf(8)][lane(64)][i(8)]
// element = w_hh[gate*256 + w*16 + (lane&15)][kf*32 + (lane>>4)*8 + i]
__global__ __launch_bounds__(256) void k_prep_whh(const float* __restrict__ whf,
                                                  const float* __restrict__ whr,
                                                  _Float16* __restrict__ whp) {
  int e = blockIdx.x * 256 + threadIdx.x;       // < 2*196608 = 393216
  int dir = e / 196608;
  int r = e - dir * 196608;
  int w = r / 12288;  int r2 = r - w * 12288;
  int gate = r2 >> 12; int r3 = r2 & 4095;
  int kf = r3 >> 9;    int r4 = r3 & 511;
  int lane = r4 >> 3;  int i = r4 & 7;
  int row = gate * 256 + w * 16 + (lane & 15);
  int col = kf * 32 + (lane >> 4) * 8 + i;
  const float* src = dir ? whr : whf;
  whp[e] = (_Float16)src[row * 256 + col];
}

// ---------------------------- xi GEMM --------------------------------------
// C[M=51200][1536] = A[M][512] * Wt[1536][512]^T + bias, all fp16 in, fp16 out.
#define BM 128
#define BN 128
#define BK 32
#define PK 40   // padded LDS leading dim (elements) -> 80B rows, 2-way banks

__global__ __launch_bounds__(256) void k_gemm(const _Float16* __restrict__ A,
                                              const _Float16* __restrict__ Wt,
                                              const float* __restrict__ bias,
                                              _Float16* __restrict__ C) {
  __shared__ _Float16 As[BM * PK];
  __shared__ _Float16 Bs[BN * PK];
  const int tid = threadIdx.x;
  const int wv = tid >> 6, ln = tid & 63;
  const int wm = wv >> 1, wn = wv & 1;
  const int jl = ln & 15, q = ln >> 4;
  const int m0 = blockIdx.x * BM, n0 = blockIdx.y * BN;

  fx4 acc[4][4];
#pragma unroll
  for (int a = 0; a < 4; ++a)
#pragma unroll
    for (int b = 0; b < 4; ++b) acc[a][b] = (fx4){0.f, 0.f, 0.f, 0.f};

  for (int kk = 0; kk < KDIM; kk += BK) {
#pragma unroll
    for (int r = 0; r < 2; ++r) {
      int chunk = r * 256 + tid;        // 512 chunks of 8 elems (16B)
      int row = chunk >> 2, k8 = chunk & 3;
      half8 av = *(const half8*)(A + (size_t)(m0 + row) * KDIM + kk + k8 * 8);
      half8 bv = *(const half8*)(Wt + (size_t)(n0 + row) * KDIM + kk + k8 * 8);
      *(half8*)(As + row * PK + k8 * 8) = av;
      *(half8*)(Bs + row * PK + k8 * 8) = bv;
    }
    __syncthreads();
    half8 af[4], bfr[4];
#pragma unroll
    for (int mt = 0; mt < 4; ++mt)
      af[mt] = *(const half8*)(As + (wm * 64 + mt * 16 + jl) * PK + q * 8);
#pragma unroll
    for (int nt = 0; nt < 4; ++nt)
      bfr[nt] = *(const half8*)(Bs + (wn * 64 + nt * 16 + jl) * PK + q * 8);
#pragma unroll
    for (int mt = 0; mt < 4; ++mt)
#pragma unroll
      for (int nt = 0; nt < 4; ++nt)
        acc[mt][nt] = __builtin_amdgcn_mfma_f32_16x16x32_f16(af[mt], bfr[nt], acc[mt][nt], 0, 0, 0);
    __syncthreads();
  }

#pragma unroll
  for (int nt = 0; nt < 4; ++nt) {
    int col = n0 + wn * 64 + nt * 16 + jl;
    float bs = bias[col];
#pragma unroll
    for (int mt = 0; mt < 4; ++mt) {
#pragma unroll
      for (int rg = 0; rg < 4; ++rg) {
        int row = m0 + wm * 64 + mt * 16 + q * 4 + rg;
        C[(size_t)row * NG + col] = (_Float16)(acc[mt][nt][rg] + bs);
      }
    }
  }
}

// ---------------------------- GRU recurrence -------------------------------
// Grid (16 batch-tiles, 2 dirs), 1024 threads (16 waves). Wave w owns hidden
// units j in [16w,16w+16). r/z weight frags in VGPRs, n frags in LDS.
// C-layout: per lane j_local = ln&15, batch m = (ln>>4)*4 + reg.
__global__ __launch_bounds__(1024) void k_gru(const _Float16* __restrict__ xi,   // [MROWS][1536]
                                              const _Float16* __restrict__ whp,  // packed
                                              const float* __restrict__ bhhf,
                                              const float* __restrict__ bhhr,
                                              _Float16* __restrict__ out) {      // [MROWS][512]
  extern __shared__ _Float16 smem_h[];
  _Float16* nlds = smem_h;            // 16*8*64*8 = 65536 elems (128KB)
  _Float16* hlds = smem_h + 65536;    // 16 rows * 264 (padded) = 4224 elems

  const int tid = threadIdx.x, w = tid >> 6, ln = tid & 63;
  const int jl = ln & 15, q = ln >> 4;
  const int bt = blockIdx.x, dir = blockIdx.y;
  const float* bhh = dir ? bhhr : bhhf;
  const int j = w * 16 + jl;

  const _Float16* wb = whp + ((size_t)dir * 16 + w) * 12288;
  half8 wr[8], wz[8];
#pragma unroll
  for (int kf = 0; kf < 8; ++kf) {
    wr[kf] = *(const half8*)(wb + kf * 512 + ln * 8);
    wz[kf] = *(const half8*)(wb + 4096 + kf * 512 + ln * 8);
    *(half8*)(nlds + (w * 8 + kf) * 512 + ln * 8) = *(const half8*)(wb + 8192 + kf * 512 + ln * 8);
  }
  const float bh_r = bhh[j], bh_z = bhh[256 + j], bh_n = bhh[512 + j];

  for (int i = tid; i < 16 * 264; i += 1024) hlds[i] = (_Float16)0.f;

  float hprev[4] = {0.f, 0.f, 0.f, 0.f};
  const long long t0 = dir ? (SEQ - 1) : 0;
  const long long xstep = dir ? -(long long)NG : (long long)NG;
  const long long ostep = dir ? -512LL : 512LL;
  const _Float16* xip[4];
  _Float16* op[4];
#pragma unroll
  for (int rg = 0; rg < 4; ++rg) {
    long long brow = bt * 16 + q * 4 + rg;
    xip[rg] = xi + (brow * SEQ + t0) * NG + dir * 768 + j;
    op[rg] = out + (brow * SEQ + t0) * 512 + dir * 256 + j;
  }
  __syncthreads();

  for (int s = 0; s < SEQ; ++s) {
    fx4 ar = (fx4){0.f,0.f,0.f,0.f}, az = ar, an = ar;
#pragma unroll
    for (int kf = 0; kf < 8; ++kf) {
      half8 a = *(const half8*)(hlds + (ln & 15) * 264 + kf * 32 + q * 8);
      half8 nb = *(const half8*)(nlds + (w * 8 + kf) * 512 + ln * 8);
      ar = __builtin_amdgcn_mfma_f32_16x16x32_f16(a, wr[kf], ar, 0, 0, 0);
      az = __builtin_amdgcn_mfma_f32_16x16x32_f16(a, wz[kf], az, 0, 0, 0);
      an = __builtin_amdgcn_mfma_f32_16x16x32_f16(a, nb, an, 0, 0, 0);
    }
    __syncthreads();   // all waves finished reading hlds
#pragma unroll
    for (int rg = 0; rg < 4; ++rg) {
      float xir = (float)xip[rg][0];
      float xiz = (float)xip[rg][256];
      float xin = (float)xip[rg][512];
      float r = 1.f / (1.f + __expf(-(ar[rg] + bh_r + xir)));
      float z = 1.f / (1.f + __expf(-(az[rg] + bh_z + xiz)));
      float gn = xin + r * (an[rg] + bh_n);
      gn = fminf(fmaxf(gn, -9.f), 9.f);
      float e2 = __expf(2.f * gn);
      float nn = (e2 - 1.f) / (e2 + 1.f);
      float h = (1.f - z) * nn + z * hprev[rg];
      hprev[rg] = h;
      _Float16 hb = (_Float16)h;
      int m = q * 4 + rg;
      hlds[m * 264 + j] = hb;
      op[rg][0] = hb;
      xip[rg] += xstep;
      op[rg] += ostep;
    }
    __syncthreads();   // h writes visible before next step's reads
  }
}

// ---------------------------- heads ----------------------------------------

__global__ __launch_bounds__(256) void k_heads1(const _Float16* __restrict__ out,
                                                const float* __restrict__ fc1w,
                                                const float* __restrict__ fc1b,
                                                const float* __restrict__ fc2w,
                                                const float* __restrict__ fc2b,
                                                float* __restrict__ y,
                                                float* __restrict__ y2) {
  int gw = (blockIdx.x * 256 + threadIdx.x) >> 6;   // wave id < 51200
  int ln = threadIdx.x & 63;
  int b = gw / SEQ, t = gw - b * SEQ;
  half8 ov = *(const half8*)(out + (size_t)gw * 512 + ln * 8);
  float o[8];
#pragma unroll
  for (int i = 0; i < 8; ++i) o[i] = (float)ov[i];

  float4 w1a = *(const float4*)(fc1w + ln * 8);
  float4 w1b = *(const float4*)(fc1w + ln * 8 + 4);
  float s1 = o[0]*w1a.x + o[1]*w1a.y + o[2]*w1a.z + o[3]*w1a.w
           + o[4]*w1b.x + o[5]*w1b.y + o[6]*w1b.z + o[7]*w1b.w;
  float s2[10];
#pragma unroll
  for (int c = 0; c < 10; ++c) {
    float4 wa = *(const float4*)(fc2w + c * 512 + ln * 8);
    float4 wbv = *(const float4*)(fc2w + c * 512 + ln * 8 + 4);
    s2[c] = o[0]*wa.x + o[1]*wa.y + o[2]*wa.z + o[3]*wa.w
          + o[4]*wbv.x + o[5]*wbv.y + o[6]*wbv.z + o[7]*wbv.w;
  }
#pragma unroll
  for (int m = 32; m; m >>= 1) {
    s1 += __shfl_xor(s1, m);
#pragma unroll
    for (int c = 0; c < 10; ++c) s2[c] += __shfl_xor(s2[c], m);
  }
  if (ln == 0) {
    y[gw] = s1 + fc1b[0];
    float* y2p = y2 + (size_t)b * 2000 + t * 10;
#pragma unroll
    for (int c = 0; c < 10; ++c) y2p[c] = s2[c] + fc2b[c];
  }
}

__device__ __forceinline__ float blkRedMax(float v, float* red, int tid) {
#pragma unroll
  for (int m = 32; m; m >>= 1) v = fmaxf(v, __shfl_xor(v, m));
  __syncthreads();
  if ((tid & 63) == 0) red[tid >> 6] = v;
  __syncthreads();
  return fmaxf(fmaxf(red[0], red[1]), fmaxf(red[2], red[3]));
}
__device__ __forceinline__ float blkRedSum(float v, float* red, int tid) {
#pragma unroll
  for (int m = 32; m; m >>= 1) v += __shfl_xor(v, m);
  __syncthreads();
  if ((tid & 63) == 0) red[tid >> 6] = v;
  __syncthreads();
  return red[0] + red[1] + red[2] + red[3];
}

__global__ __launch_bounds__(256) void k_heads2(const float* __restrict__ y,
                                                const float* __restrict__ y2,
                                                float* __restrict__ y3) {
  __shared__ float sp[SEQ];
  __shared__ float se[2000];
  __shared__ float red[4];
  int b = blockIdx.x, tid = threadIdx.x;

  float v = (tid < SEQ) ? y[(size_t)b * SEQ + tid] : -3.0e38f;
  float mx = blkRedMax(v, red, tid);
  float e = (tid < SEQ) ? __expf(v - mx) : 0.f;
  float sum = blkRedSum(e, red, tid);
  if (tid < SEQ) sp[tid] = e / (sum * 10.f);

  float vv[8];
  float lm = -3.0e38f;
#pragma unroll
  for (int r = 0; r < 8; ++r) {
    int k = tid + r * 256;
    vv[r] = (k < 2000) ? y2[(size_t)b * 2000 + k] : -3.0e38f;
    lm = fmaxf(lm, vv[r]);
  }
  float mx2 = blkRedMax(lm, red, tid);
  float ls = 0.f;
#pragma unroll
  for (int r = 0; r < 8; ++r) {
    int k = tid + r * 256;
    if (k < 2000) { float ee = __expf(vv[r] - mx2); se[k] = ee; ls += ee; }
  }
  float sum2 = blkRedSum(ls, red, tid);
  __syncthreads();
  float inv = 1.f / sum2;
#pragma unroll
  for (int r = 0; r < 8; ++r) {
    int k = tid + r * 256;
    if (k < 2000) y3[(size_t)b * 2000 + k] = se[k] * inv + sp[k / 10];
  }
}

// ---------------------------- launch ---------------------------------------

extern "C" void kernel_launch(void* const* d_in, const int* in_sizes, int n_in,
                              void* d_out, int out_size, void* d_ws, size_t ws_size,
                              hipStream_t stream) {
  const float* x     = (const float*)d_in[0];
  const float* wih0  = (const float*)d_in[1];
  const float* whh0  = (const float*)d_in[2];
  const float* bih0  = (const float*)d_in[3];
  const float* bhh0  = (const float*)d_in[4];
  const float* wih0r = (const float*)d_in[5];
  const float* whh0r = (const float*)d_in[6];
  const float* bih0r = (const float*)d_in[7];
  const float* bhh0r = (const float*)d_in[8];
  const float* wih1  = (const float*)d_in[9];
  const float* whh1  = (const float*)d_in[10];
  const float* bih1  = (const float*)d_in[11];
  const float* bhh1  = (const float*)d_in[12];
  const float* wih1r = (const float*)d_in[13];
  const float* whh1r = (const float*)d_in[14];
  const float* bih1r = (const float*)d_in[15];
  const float* bhh1r = (const float*)d_in[16];
  const float* fc1w  = (const float*)d_in[17];
  const float* fc1b  = (const float*)d_in[18];
  const float* fc2w  = (const float*)d_in[19];
  const float* fc2b  = (const float*)d_in[20];

  char* ws = (char*)d_ws;
  _Float16* xh    = (_Float16*)(ws + 0);            //  52,428,800 B
  _Float16* xi    = (_Float16*)(ws + 52428800);     // 157,286,400 B (reused both layers)
  _Float16* l0    = (_Float16*)(ws + 209715200);    //  52,428,800 B
  _Float16* outh  = (_Float16*)(ws + 262144000);    //  52,428,800 B
  _Float16* wcat0 = (_Float16*)(ws + 314572800);    //   1,572,864 B
  _Float16* wcat1 = (_Float16*)(ws + 316145664);
  _Float16* whp0  = (_Float16*)(ws + 317718528);    //     786,432 B
  _Float16* whp1  = (_Float16*)(ws + 318504960);
  float*    bcat0 = (float*)(ws + 319291392);
  float*    bcat1 = (float*)(ws + 319297536);       // end: 319,303,680 B

  float* y  = (float*)d_out;
  float* y2 = (float*)d_out + 51200;
  float* y3 = (float*)d_out + 563200;

  // prep (independent)
  k_cast_x<<<25600, 256, 0, stream>>>((const float4*)x, (half4v*)xh, 6553600);
  k_prep_wih<<<3072, 256, 0, stream>>>(wih0, wih0r, bih0, bih0r, wcat0, bcat0);
  k_prep_wih<<<3072, 256, 0, stream>>>(wih1, wih1r, bih1, bih1r, wcat1, bcat1);
  k_prep_whh<<<1536, 256, 0, stream>>>(whh0, whh0r, whp0);
  k_prep_whh<<<1536, 256, 0, stream>>>(whh1, whh1r, whp1);

  hipFuncSetAttribute(reinterpret_cast<const void*>(k_gru),
                      hipFuncAttributeMaxDynamicSharedMemorySize, 139520);

  // layer 0
  k_gemm<<<dim3(400, 12), 256, 0, stream>>>(xh, wcat0, bcat0, xi);
  k_gru<<<dim3(16, 2), 1024, 139520, stream>>>(xi, whp0, bhh0, bhh0r, l0);
  // layer 1
  k_gemm<<<dim3(400, 12), 256, 0, stream>>>(l0, wcat1, bcat1, xi);
  k_gru<<<dim3(16, 2), 1024, 139520, stream>>>(xi, whp1, bhh1, bhh1r, outh);
  // heads
  k_heads1<<<12800, 256, 0, stream>>>(outh, fc1w, fc1b, fc2w, fc2b, y, y2);
  k_heads2<<<256, 256, 0, stream>>>(y, y2, y3);
}

// Round 2
// 1595.842 us; speedup vs baseline: 1.1225x; 1.1225x over previous
//
#include <hip/hip_runtime.h>

// ---------------------------------------------------------------------------
// Bidirectional 2-layer GRU (B=256, L=200, IN=512, H=256) + FC heads.
// R2: gru = resident r/z weights (launch_bounds cap 128), xi prefetch,
//     single barrier/step via double-buffered h.
//     gemm = m97-style global_load_lds width-16 staging + coalesced epilogue.
// ---------------------------------------------------------------------------

typedef _Float16 half8 __attribute__((ext_vector_type(8)));
typedef _Float16 half4v __attribute__((ext_vector_type(4)));
typedef float fx4 __attribute__((ext_vector_type(4)));

#define BATCH 256
#define SEQ   200
#define HID   256
#define MROWS (BATCH*SEQ)   // 51200
#define NG    1536          // 3H * 2 directions
#define KDIM  512

__device__ __forceinline__ void gload_lds16(const _Float16* g, _Float16* l) {
  __builtin_amdgcn_global_load_lds((const __attribute__((address_space(1))) void*)g,
                                   (__attribute__((address_space(3))) void*)l, 16, 0, 0);
}

// ---------------------------- prep kernels ---------------------------------

__global__ __launch_bounds__(256) void k_cast_x(const float4* __restrict__ x,
                                                half4v* __restrict__ xh, int n4) {
  int i = blockIdx.x * 256 + threadIdx.x;
  if (i < n4) {
    float4 v = x[i];
    half4v o;
    o[0] = (_Float16)v.x; o[1] = (_Float16)v.y; o[2] = (_Float16)v.z; o[3] = (_Float16)v.w;
    xh[i] = o;
  }
}

__global__ __launch_bounds__(256) void k_prep_wih(const float* __restrict__ wf,
                                                  const float* __restrict__ wr,
                                                  const float* __restrict__ bf_,
                                                  const float* __restrict__ br_,
                                                  _Float16* __restrict__ wcat,
                                                  float* __restrict__ bcat) {
  int idx = blockIdx.x * 256 + threadIdx.x;     // < 1536*512
  int n = idx >> 9;
  float v = (n < 768) ? wf[idx] : wr[idx - 768 * 512];
  wcat[idx] = (_Float16)v;
  if (idx < 1536) bcat[idx] = (idx < 768) ? bf_[idx] : br_[idx - 768];
}

// Pack w_hh into MFMA B-fragment order: [dir][w(16)][gate(3)][kf(8)][lane(64)][i(8)]
__global__ __launch_bounds__(256) void k_prep_whh(const float* __restrict__ whf,
                                                  const float* __restrict__ whr,
                                                  _Float16* __restrict__ whp) {
  int e = blockIdx.x * 256 + threadIdx.x;       // < 2*196608
  int dir = e / 196608;
  int r = e - dir * 196608;
  int w = r / 12288;  int r2 = r - w * 12288;
  int gate = r2 >> 12; int r3 = r2 & 4095;
  int kf = r3 >> 9;    int r4 = r3 & 511;
  int lane = r4 >> 3;  int i = r4 & 7;
  int row = gate * 256 + w * 16 + (lane & 15);
  int col = kf * 32 + (lane >> 4) * 8 + i;
  const float* src = dir ? whr : whf;
  whp[e] = (_Float16)src[row * 256 + col];
}

// ---------------------------- xi GEMM (m97 structure) ----------------------
// C[51200][1536] = A[51200][512] * Wt[1536][512]^T + bias. fp16 in/out.
__global__ __launch_bounds__(256) void k_gemm(const _Float16* __restrict__ A,
                                              const _Float16* __restrict__ Wt,
                                              const float* __restrict__ bias,
                                              _Float16* __restrict__ C) {
  __shared__ __align__(16) _Float16 As[128 * 32];
  __shared__ __align__(16) _Float16 Bs[128 * 32];
  const int tid = threadIdx.x;
  const int wv = tid >> 6, ln = tid & 63;
  const int wm = wv >> 1, wn = wv & 1;
  const int jl = ln & 15, q = ln >> 4;
  const int m0 = blockIdx.x * 128, n0 = blockIdx.y * 128;

  const int r0 = tid >> 2, k80 = (tid & 3) * 8;   // staging chunk tid
  const int r1 = r0 + 64;                          // staging chunk tid+256

  fx4 acc[4][4];
#pragma unroll
  for (int a = 0; a < 4; ++a)
#pragma unroll
    for (int b = 0; b < 4; ++b) acc[a][b] = (fx4){0.f, 0.f, 0.f, 0.f};

  for (int kk = 0; kk < KDIM; kk += 32) {
    gload_lds16(A  + (size_t)(m0 + r0) * KDIM + kk + k80, As + tid * 8);
    gload_lds16(A  + (size_t)(m0 + r1) * KDIM + kk + k80, As + (tid + 256) * 8);
    gload_lds16(Wt + (size_t)(n0 + r0) * KDIM + kk + k80, Bs + tid * 8);
    gload_lds16(Wt + (size_t)(n0 + r1) * KDIM + kk + k80, Bs + (tid + 256) * 8);
    __syncthreads();   // drains vmcnt -> LDS staged
    half8 af[4], bfr[4];
#pragma unroll
    for (int mt = 0; mt < 4; ++mt)
      af[mt] = *(const half8*)(As + (wm * 64 + mt * 16 + jl) * 32 + q * 8);
#pragma unroll
    for (int nt = 0; nt < 4; ++nt)
      bfr[nt] = *(const half8*)(Bs + (wn * 64 + nt * 16 + jl) * 32 + q * 8);
#pragma unroll
    for (int mt = 0; mt < 4; ++mt)
#pragma unroll
      for (int nt = 0; nt < 4; ++nt)
        acc[mt][nt] = __builtin_amdgcn_mfma_f32_16x16x32_f16(af[mt], bfr[nt], acc[mt][nt], 0, 0, 0);
    __syncthreads();
  }

  // coalesced epilogue: stage 32x128 fp16 chunks through As
  float bsv[4];
#pragma unroll
  for (int nt = 0; nt < 4; ++nt) bsv[nt] = bias[n0 + wn * 64 + nt * 16 + jl];

  for (int mt = 0; mt < 4; ++mt) {
#pragma unroll
    for (int nt = 0; nt < 4; ++nt)
#pragma unroll
      for (int rg = 0; rg < 4; ++rg)
        As[(wm * 16 + q * 4 + rg) * 128 + wn * 64 + nt * 16 + jl] =
            (_Float16)(acc[mt][nt][rg] + bsv[nt]);
    __syncthreads();
#pragma unroll
    for (int i = 0; i < 2; ++i) {
      int idx = i * 256 + tid;          // 0..511
      int rl = idx >> 4, c8 = idx & 15;
      int grow = m0 + (rl >> 4) * 64 + mt * 16 + (rl & 15);
      *(half8*)(C + (size_t)grow * NG + n0 + c8 * 8) = *(const half8*)(As + rl * 128 + c8 * 8);
    }
    __syncthreads();
  }
}

// ---------------------------- GRU recurrence -------------------------------
// 32 blocks (16 batch-tiles x 2 dirs), 16 waves. Wave w owns hidden j in
// [16w,16w+16). r/z weights resident in VGPRs (cap 128 via launch_bounds),
// n weights in LDS. h double-buffered in LDS -> one barrier/step. xi
// prefetched one step ahead into registers.
__global__ __launch_bounds__(1024, 4) void k_gru(const _Float16* __restrict__ xi,
                                                 const _Float16* __restrict__ whp,
                                                 const float* __restrict__ bhhf,
                                                 const float* __restrict__ bhhr,
                                                 _Float16* __restrict__ out) {
  extern __shared__ _Float16 smem[];
  _Float16* nlds = smem;                    // 65536 elems (128KB)
  _Float16* hb0  = smem + 65536;            // 16*264
  _Float16* hb1  = smem + 65536 + 4224;     // 16*264  (total 147968 B)

  const int tid = threadIdx.x, w = tid >> 6, ln = tid & 63;
  const int jl = ln & 15, q = ln >> 4;
  const int bt = blockIdx.x, dir = blockIdx.y;
  const float* bhh = dir ? bhhr : bhhf;
  const int j = w * 16 + jl;

  const _Float16* wb = whp + ((size_t)dir * 16 + w) * 12288;
  half8 wr[8], wz[8];
#pragma unroll
  for (int kf = 0; kf < 8; ++kf) {
    wr[kf] = *(const half8*)(wb + kf * 512 + ln * 8);
    wz[kf] = *(const half8*)(wb + 4096 + kf * 512 + ln * 8);
    *(half8*)(nlds + (w * 8 + kf) * 512 + ln * 8) = *(const half8*)(wb + 8192 + kf * 512 + ln * 8);
  }
  const float bh_r = bhh[j], bh_z = bhh[256 + j], bh_n = bhh[512 + j];

  for (int i = tid; i < 4224; i += 1024) hb0[i] = (_Float16)0.f;

  const long long t0 = dir ? (SEQ - 1) : 0;
  const int xstep = dir ? -NG : NG;
  const int ostep = dir ? -512 : 512;
  const _Float16* xp = xi + ((size_t)((bt * 16 + q * 4) * SEQ) + t0) * NG + dir * 768 + j;
  _Float16* op = out + ((size_t)((bt * 16 + q * 4) * SEQ) + t0) * 512 + dir * 256 + j;

  // preload xi for s=0
  _Float16 cxr[4], cxz[4], cxn[4];
#pragma unroll
  for (int rg = 0; rg < 4; ++rg) {
    cxr[rg] = xp[rg * 307200];
    cxz[rg] = xp[rg * 307200 + 256];
    cxn[rg] = xp[rg * 307200 + 512];
  }

  float hprev[4] = {0.f, 0.f, 0.f, 0.f};
  __syncthreads();   // nlds + hb0 ready

  for (int s = 0; s < SEQ; ++s) {
    // prefetch xi for s+1 (in flight during MFMA phase)
    const _Float16* xq = xp + ((s < SEQ - 1) ? xstep : 0);
    _Float16 nxr[4], nxz[4], nxn[4];
#pragma unroll
    for (int rg = 0; rg < 4; ++rg) {
      nxr[rg] = xq[rg * 307200];
      nxz[rg] = xq[rg * 307200 + 256];
      nxn[rg] = xq[rg * 307200 + 512];
    }

    const _Float16* hr = (s & 1) ? hb1 : hb0;
    _Float16*       hw = (s & 1) ? hb0 : hb1;

    fx4 ar = (fx4){0.f,0.f,0.f,0.f}, az = ar, an = ar;
#pragma unroll
    for (int kf = 0; kf < 8; ++kf) {
      half8 a  = *(const half8*)(hr + jl * 264 + kf * 32 + q * 8);
      half8 nb = *(const half8*)(nlds + (w * 8 + kf) * 512 + ln * 8);
      ar = __builtin_amdgcn_mfma_f32_16x16x32_f16(a, wr[kf], ar, 0, 0, 0);
      az = __builtin_amdgcn_mfma_f32_16x16x32_f16(a, wz[kf], az, 0, 0, 0);
      an = __builtin_amdgcn_mfma_f32_16x16x32_f16(a, nb,     an, 0, 0, 0);
    }

#pragma unroll
    for (int rg = 0; rg < 4; ++rg) {
      float r = 1.f / (1.f + __expf(-(ar[rg] + bh_r + (float)cxr[rg])));
      float z = 1.f / (1.f + __expf(-(az[rg] + bh_z + (float)cxz[rg])));
      float gn = (float)cxn[rg] + r * (an[rg] + bh_n);
      gn = fminf(fmaxf(gn, -9.f), 9.f);
      float e2 = __expf(2.f * gn);
      float nn = (e2 - 1.f) / (e2 + 1.f);
      float h = (1.f - z) * nn + z * hprev[rg];
      hprev[rg] = h;
      _Float16 hb = (_Float16)h;
      hw[(q * 4 + rg) * 264 + j] = hb;
      op[rg * 102400] = hb;
    }
#pragma unroll
    for (int rg = 0; rg < 4; ++rg) { cxr[rg] = nxr[rg]; cxz[rg] = nxz[rg]; cxn[rg] = nxn[rg]; }
    xp = xq;
    op += ostep;
    __syncthreads();   // h(s+1) visible; also covers WAR on read buffer
  }
}

// ---------------------------- heads ----------------------------------------

__global__ __launch_bounds__(256) void k_heads1(const _Float16* __restrict__ out,
                                                const float* __restrict__ fc1w,
                                                const float* __restrict__ fc1b,
                                                const float* __restrict__ fc2w,
                                                const float* __restrict__ fc2b,
                                                float* __restrict__ y,
                                                float* __restrict__ y2) {
  int gw = (blockIdx.x * 256 + threadIdx.x) >> 6;   // wave id < 51200
  int ln = threadIdx.x & 63;
  int b = gw / SEQ, t = gw - b * SEQ;
  half8 ov = *(const half8*)(out + (size_t)gw * 512 + ln * 8);
  float o[8];
#pragma unroll
  for (int i = 0; i < 8; ++i) o[i] = (float)ov[i];

  float4 w1a = *(const float4*)(fc1w + ln * 8);
  float4 w1b = *(const float4*)(fc1w + ln * 8 + 4);
  float s1 = o[0]*w1a.x + o[1]*w1a.y + o[2]*w1a.z + o[3]*w1a.w
           + o[4]*w1b.x + o[5]*w1b.y + o[6]*w1b.z + o[7]*w1b.w;
  float s2[10];
#pragma unroll
  for (int c = 0; c < 10; ++c) {
    float4 wa = *(const float4*)(fc2w + c * 512 + ln * 8);
    float4 wbv = *(const float4*)(fc2w + c * 512 + ln * 8 + 4);
    s2[c] = o[0]*wa.x + o[1]*wa.y + o[2]*wa.z + o[3]*wa.w
          + o[4]*wbv.x + o[5]*wbv.y + o[6]*wbv.z + o[7]*wbv.w;
  }
#pragma unroll
  for (int m = 32; m; m >>= 1) {
    s1 += __shfl_xor(s1, m);
#pragma unroll
    for (int c = 0; c < 10; ++c) s2[c] += __shfl_xor(s2[c], m);
  }
  if (ln == 0) {
    y[gw] = s1 + fc1b[0];
    float* y2p = y2 + (size_t)b * 2000 + t * 10;
#pragma unroll
    for (int c = 0; c < 10; ++c) y2p[c] = s2[c] + fc2b[c];
  }
}

__device__ __forceinline__ float blkRedMax(float v, float* red, int tid) {
#pragma unroll
  for (int m = 32; m; m >>= 1) v = fmaxf(v, __shfl_xor(v, m));
  __syncthreads();
  if ((tid & 63) == 0) red[tid >> 6] = v;
  __syncthreads();
  return fmaxf(fmaxf(red[0], red[1]), fmaxf(red[2], red[3]));
}
__device__ __forceinline__ float blkRedSum(float v, float* red, int tid) {
#pragma unroll
  for (int m = 32; m; m >>= 1) v += __shfl_xor(v, m);
  __syncthreads();
  if ((tid & 63) == 0) red[tid >> 6] = v;
  __syncthreads();
  return red[0] + red[1] + red[2] + red[3];
}

__global__ __launch_bounds__(256) void k_heads2(const float* __restrict__ y,
                                                const float* __restrict__ y2,
                                                float* __restrict__ y3) {
  __shared__ float sp[SEQ];
  __shared__ float se[2000];
  __shared__ float red[4];
  int b = blockIdx.x, tid = threadIdx.x;

  float v = (tid < SEQ) ? y[(size_t)b * SEQ + tid] : -3.0e38f;
  float mx = blkRedMax(v, red, tid);
  float e = (tid < SEQ) ? __expf(v - mx) : 0.f;
  float sum = blkRedSum(e, red, tid);
  if (tid < SEQ) sp[tid] = e / (sum * 10.f);

  float vv[8];
  float lm = -3.0e38f;
#pragma unroll
  for (int r = 0; r < 8; ++r) {
    int k = tid + r * 256;
    vv[r] = (k < 2000) ? y2[(size_t)b * 2000 + k] : -3.0e38f;
    lm = fmaxf(lm, vv[r]);
  }
  float mx2 = blkRedMax(lm, red, tid);
  float ls = 0.f;
#pragma unroll
  for (int r = 0; r < 8; ++r) {
    int k = tid + r * 256;
    if (k < 2000) { float ee = __expf(vv[r] - mx2); se[k] = ee; ls += ee; }
  }
  float sum2 = blkRedSum(ls, red, tid);
  __syncthreads();
  float inv = 1.f / sum2;
#pragma unroll
  for (int r = 0; r < 8; ++r) {
    int k = tid + r * 256;
    if (k < 2000) y3[(size_t)b * 2000 + k] = se[k] * inv + sp[k / 10];
  }
}

// ---------------------------- launch ---------------------------------------

extern "C" void kernel_launch(void* const* d_in, const int* in_sizes, int n_in,
                              void* d_out, int out_size, void* d_ws, size_t ws_size,
                              hipStream_t stream) {
  const float* x     = (const float*)d_in[0];
  const float* wih0  = (const float*)d_in[1];
  const float* whh0  = (const float*)d_in[2];
  const float* bih0  = (const float*)d_in[3];
  const float* bhh0  = (const float*)d_in[4];
  const float* wih0r = (const float*)d_in[5];
  const float* whh0r = (const float*)d_in[6];
  const float* bih0r = (const float*)d_in[7];
  const float* bhh0r = (const float*)d_in[8];
  const float* wih1  = (const float*)d_in[9];
  const float* whh1  = (const float*)d_in[10];
  const float* bih1  = (const float*)d_in[11];
  const float* bhh1  = (const float*)d_in[12];
  const float* wih1r = (const float*)d_in[13];
  const float* whh1r = (const float*)d_in[14];
  const float* bih1r = (const float*)d_in[15];
  const float* bhh1r = (const float*)d_in[16];
  const float* fc1w  = (const float*)d_in[17];
  const float* fc1b  = (const float*)d_in[18];
  const float* fc2w  = (const float*)d_in[19];
  const float* fc2b  = (const float*)d_in[20];

  char* ws = (char*)d_ws;
  _Float16* xh    = (_Float16*)(ws + 0);            //  52,428,800 B
  _Float16* xi    = (_Float16*)(ws + 52428800);     // 157,286,400 B (reused both layers)
  _Float16* l0    = (_Float16*)(ws + 209715200);    //  52,428,800 B
  _Float16* outh  = (_Float16*)(ws + 262144000);    //  52,428,800 B
  _Float16* wcat0 = (_Float16*)(ws + 314572800);
  _Float16* wcat1 = (_Float16*)(ws + 316145664);
  _Float16* whp0  = (_Float16*)(ws + 317718528);
  _Float16* whp1  = (_Float16*)(ws + 318504960);
  float*    bcat0 = (float*)(ws + 319291392);
  float*    bcat1 = (float*)(ws + 319297536);

  float* y  = (float*)d_out;
  float* y2 = (float*)d_out + 51200;
  float* y3 = (float*)d_out + 563200;

  k_cast_x<<<25600, 256, 0, stream>>>((const float4*)x, (half4v*)xh, 6553600);
  k_prep_wih<<<3072, 256, 0, stream>>>(wih0, wih0r, bih0, bih0r, wcat0, bcat0);
  k_prep_wih<<<3072, 256, 0, stream>>>(wih1, wih1r, bih1, bih1r, wcat1, bcat1);
  k_prep_whh<<<1536, 256, 0, stream>>>(whh0, whh0r, whp0);
  k_prep_whh<<<1536, 256, 0, stream>>>(whh1, whh1r, whp1);

  hipFuncSetAttribute(reinterpret_cast<const void*>(k_gru),
                      hipFuncAttributeMaxDynamicSharedMemorySize, 147968);

  k_gemm<<<dim3(400, 12), 256, 0, stream>>>(xh, wcat0, bcat0, xi);
  k_gru<<<dim3(16, 2), 1024, 147968, stream>>>(xi, whp0, bhh0, bhh0r, l0);
  k_gemm<<<dim3(400, 12), 256, 0, stream>>>(l0, wcat1, bcat1, xi);
  k_gru<<<dim3(16, 2), 1024, 147968, stream>>>(xi, whp1, bhh1, bhh1r, outh);
  k_heads1<<<12800, 256, 0, stream>>>(outh, fc1w, fc1b, fc2w, fc2b, y, y2);
  k_heads2<<<256, 256, 0, stream>>>(y, y2, y3);
}